// Round 1
// baseline (3669.612 us; speedup 1.0000x reference)
//
#include <hip/hip_runtime.h>
#include <hip/hip_bf16.h>

#define BB 1024
#define LL 2048
#define DD 64
#define KK 8192

__device__ __forceinline__ float leaky(float v){ return v > 0.0f ? v : 0.001f*v; }

// ws layout: [0, 32768) W3t (8192 f32) | [32768, 36864) idx (1024 i32) | [36864, 40960) loss partials (1024 f32)

__global__ void w3_transpose_kernel(const float* __restrict__ W3, float* __restrict__ W3t){
    int i = blockIdx.x*256 + threadIdx.x;           // 8192 elements
    if (i < 64*128){ int o = i & 63; int c = i >> 6; W3t[c*64+o] = W3[o*128+c]; }
}

// Fused conv1x1 stack (3->64->128->64) + leaky + global max over L.
// One block per batch element; each thread processes 8 positions.
__global__ __launch_bounds__(256, 1) void encoder_kernel(
    const float* __restrict__ x,
    const float* __restrict__ W1, const float* __restrict__ b1,
    const float* __restrict__ W2, const float* __restrict__ b2,
    const float* __restrict__ W3t, const float* __restrict__ b3,
    float* __restrict__ z_out)
{
    const int b = blockIdx.x;
    const int t = threadIdx.x;
    const float* xb = x + (size_t)b*3*LL;

    float h3max[64];
    #pragma unroll
    for (int o=0;o<64;o++) h3max[o] = -__builtin_inff();

    for (int i=0;i<LL/256;i++){
        const int l = t + 256*i;
        const float x0 = xb[l], x1 = xb[LL+l], x2 = xb[2*LL+l];
        float h1[64];
        #pragma unroll
        for (int o=0;o<64;o++){
            float v = fmaf(W1[o*3+0], x0, fmaf(W1[o*3+1], x1, fmaf(W1[o*3+2], x2, b1[o])));
            h1[o] = leaky(v);
        }
        float h3[64];
        #pragma unroll
        for (int o=0;o<64;o++) h3[o] = b3[o];
        #pragma unroll 2
        for (int o2=0;o2<128;o2++){
            const float* w2r = W2 + o2*64;        // lane-uniform -> s_load
            float v0=0.f,v1=0.f,v2=0.f,v3=0.f;    // 4 chains for ILP
            #pragma unroll
            for (int c=0;c<64;c+=4){
                v0 = fmaf(w2r[c+0], h1[c+0], v0);
                v1 = fmaf(w2r[c+1], h1[c+1], v1);
                v2 = fmaf(w2r[c+2], h1[c+2], v2);
                v3 = fmaf(w2r[c+3], h1[c+3], v3);
            }
            float v = leaky((v0+v1)+(v2+v3) + b2[o2]);
            const float* w3r = W3t + o2*64;       // contiguous -> s_load_dwordx16
            #pragma unroll
            for (int o3=0;o3<64;o3++) h3[o3] = fmaf(w3r[o3], v, h3[o3]);
        }
        #pragma unroll
        for (int o=0;o<64;o++) h3max[o] = fmaxf(h3max[o], h3[o]);
    }

    // reduce max across the 64 lanes of each wave
    #pragma unroll
    for (int o=0;o<64;o++){
        float v = h3max[o];
        #pragma unroll
        for (int s=32;s>0;s>>=1) v = fmaxf(v, __shfl_xor(v, s, 64));
        h3max[o] = v;
    }
    __shared__ float red[4][64];
    const int wave = t>>6, lane = t&63;
    if (lane==0){
        #pragma unroll
        for (int o=0;o<64;o++) red[wave][o] = h3max[o];
    }
    __syncthreads();
    if (t < 64){
        float v = fmaxf(fmaxf(red[0][t], red[1][t]), fmaxf(red[2][t], red[3][t]));
        z_out[(size_t)b*64 + t] = v;
    }
}

// Nearest codebook entry per batch row. dist = sum((z-c)^2); argmin invariant.
__global__ __launch_bounds__(256, 1) void vq_kernel(
    const float* __restrict__ z, const float* __restrict__ cb, int* __restrict__ idx_out)
{
    const int b = blockIdx.x;
    const int t = threadIdx.x;
    float zr[64];
    #pragma unroll
    for (int d=0; d<64; d+=4){
        float4 zv = *(const float4*)(z + (size_t)b*64 + d);
        zr[d]=zv.x; zr[d+1]=zv.y; zr[d+2]=zv.z; zr[d+3]=zv.w;
    }
    float best = __builtin_inff(); int bidx = 0;
    for (int k = t; k < KK; k += 256){
        const float4* c4 = (const float4*)(cb + (size_t)k*64);
        float d0=0.f,d1=0.f,d2=0.f,d3=0.f;
        #pragma unroll
        for (int q=0;q<16;q++){
            float4 cv = c4[q];
            float t0 = zr[q*4+0]-cv.x; d0 = fmaf(t0,t0,d0);
            float t1 = zr[q*4+1]-cv.y; d1 = fmaf(t1,t1,d1);
            float t2 = zr[q*4+2]-cv.z; d2 = fmaf(t2,t2,d2);
            float t3 = zr[q*4+3]-cv.w; d3 = fmaf(t3,t3,d3);
        }
        float dist = (d0+d1)+(d2+d3);
        if (dist < best){ best = dist; bidx = k; }
    }
    __shared__ float sb[256];
    __shared__ int   si[256];
    sb[t]=best; si[t]=bidx;
    __syncthreads();
    for (int s=128; s>0; s>>=1){
        if (t < s){
            float ob = sb[t+s]; int oi = si[t+s];
            if (ob < sb[t] || (ob == sb[t] && oi < si[t])){ sb[t]=ob; si[t]=oi; }
        }
        __syncthreads();
    }
    if (t==0) idx_out[b] = si[0];
}

// Decoder (dense 64->128->64->3) + per-b loss partial sum.
__global__ __launch_bounds__(128, 1) void decoder_kernel(
    const float* __restrict__ z, const int* __restrict__ idx,
    const float* __restrict__ cb,
    const float* __restrict__ U1, const float* __restrict__ c1,
    const float* __restrict__ U2, const float* __restrict__ c2,
    const float* __restrict__ U3, const float* __restrict__ c3,
    float* __restrict__ xrec, float* __restrict__ loss_part)
{
    const int b = blockIdx.x;
    const int t = threadIdx.x;
    __shared__ float zst[64];
    __shared__ float g1[128];
    __shared__ float g2[64];
    const int kk = idx[b];
    if (t < 64){
        float zv = z[(size_t)b*64 + t];
        float zq = cb[(size_t)kk*64 + t];
        float diff = zq - zv;
        zst[t] = zv + diff;                 // straight-through forward value
        float p = diff*diff;
        #pragma unroll
        for (int s=32;s>0;s>>=1) p += __shfl_xor(p, s, 64);
        if (t==0) loss_part[b] = p;
    }
    __syncthreads();
    {
        float v = c1[t];
        #pragma unroll
        for (int d=0; d<64; d++) v = fmaf(zst[d], U1[d*128+t], v);
        g1[t] = leaky(v);
    }
    __syncthreads();
    if (t < 64){
        float v = c2[t];
        #pragma unroll
        for (int j=0;j<128;j++) v = fmaf(g1[j], U2[j*64+t], v);
        g2[t] = leaky(v);
    }
    __syncthreads();
    if (t < 3){
        float v = c3[t];
        #pragma unroll
        for (int j=0;j<64;j++) v = fmaf(g2[j], U3[j*3+t], v);
        xrec[(size_t)b*3 + t] = v;
    }
}

__global__ __launch_bounds__(256, 1) void loss_kernel(
    const float* __restrict__ loss_part, float* __restrict__ out)
{
    const int t = threadIdx.x;
    float s = 0.f;
    for (int i=t;i<BB;i+=256) s += loss_part[i];
    #pragma unroll
    for (int sh=32;sh>0;sh>>=1) s += __shfl_xor(s, sh, 64);
    __shared__ float w[4];
    if ((t&63)==0) w[t>>6] = s;
    __syncthreads();
    if (t==0) out[0] = (w[0]+w[1]+w[2]+w[3]) * (1.25f / 65536.0f);
}

extern "C" void kernel_launch(void* const* d_in, const int* in_sizes, int n_in,
                              void* d_out, int out_size, void* d_ws, size_t ws_size,
                              hipStream_t stream)
{
    const float* x  = (const float*)d_in[0];
    const float* W1 = (const float*)d_in[1];
    const float* b1 = (const float*)d_in[2];
    const float* W2 = (const float*)d_in[3];
    const float* b2 = (const float*)d_in[4];
    const float* W3 = (const float*)d_in[5];
    const float* b3 = (const float*)d_in[6];
    const float* cb = (const float*)d_in[7];
    const float* U1 = (const float*)d_in[8];
    const float* c1 = (const float*)d_in[9];
    const float* U2 = (const float*)d_in[10];
    const float* c2 = (const float*)d_in[11];
    const float* U3 = (const float*)d_in[12];
    const float* c3 = (const float*)d_in[13];

    float* out  = (float*)d_out;
    float* xrec = out;              // [1024*3]
    float* loss = out + 3072;       // [1]
    float* z    = out + 3073;       // [1024*64]

    char*  ws  = (char*)d_ws;
    float* W3t = (float*)ws;                    // 8192 f32
    int*   idx = (int*)(ws + 32768);            // 1024 i32
    float* lp  = (float*)(ws + 36864);          // 1024 f32

    hipLaunchKernelGGL(w3_transpose_kernel, dim3(32), dim3(256), 0, stream, W3, W3t);
    hipLaunchKernelGGL(encoder_kernel, dim3(BB), dim3(256), 0, stream,
                       x, W1, b1, W2, b2, W3t, b3, z);
    hipLaunchKernelGGL(vq_kernel, dim3(BB), dim3(256), 0, stream, z, cb, idx);
    hipLaunchKernelGGL(decoder_kernel, dim3(BB), dim3(128), 0, stream,
                       z, idx, cb, U1, c1, U2, c2, U3, c3, xrec, lp);
    hipLaunchKernelGGL(loss_kernel, dim3(1), dim3(256), 0, stream, lp, loss);
}

// Round 2
// 471.915 us; speedup vs baseline: 7.7760x; 7.7760x over previous
//
#include <hip/hip_runtime.h>
#include <hip/hip_bf16.h>

#define BB 1024
#define LL 2048
#define KK 8192

typedef _Float16 f16x8 __attribute__((ext_vector_type(8)));
typedef _Float16 f16x2 __attribute__((ext_vector_type(2)));
typedef float    f32x4 __attribute__((ext_vector_type(4)));

__device__ __forceinline__ float leakyf(float v){ return fmaxf(v, 0.001f*v); }

// ---------------- encoder: fused conv1x1 (3->64->128->64) + global max over L ----------------
// grid = 1024 (one block per b), 256 threads = 4 waves. Each wave does 16 positions/iter,
// block covers 64 positions/iter, 32 iters over L=2048.
// Weights live in registers as MFMA fragments (W2: 64 VGPR/lane, W3: 64 VGPR/lane).
// h2 goes C-layout -> LDS (fp16, padded stride) -> A-layout for layer 3. Wave-private, no barriers.
__global__ __launch_bounds__(256, 2) void encoder_mfma(
    const float* __restrict__ x,
    const float* __restrict__ W1, const float* __restrict__ b1,
    const float* __restrict__ W2, const float* __restrict__ b2,
    const float* __restrict__ W3, const float* __restrict__ b3,
    float* __restrict__ z_out)
{
    const int b    = blockIdx.x;
    const int t    = threadIdx.x;
    const int wave = t >> 6;
    const int lane = t & 63;
    const int col  = lane & 15;   // MFMA n / m index
    const int quad = lane >> 4;   // MFMA k-group / row-group

    // 16 rows * 136 halves (272B stride: 17*16B, breaks the 256B same-bank pattern)
    __shared__ __align__(16) _Float16 h2lds[4*16*136];
    __shared__ float ldsB2[128];
    __shared__ float red[4][64];

    if (t < 128) ldsB2[t] = b2[t];

    // ---- B-fragments for layer 2: B[k=c][n=o2] = W2[o2][c], o2 = nt*16+col, c = quad*8+32ks+j
    f16x8 w2f[2][8];
    #pragma unroll
    for (int ks=0; ks<2; ks++){
        #pragma unroll
        for (int nt=0; nt<8; nt++){
            const float* p = W2 + (nt*16+col)*64 + quad*8 + 32*ks;
            f16x8 f;
            #pragma unroll
            for (int j=0;j<8;j++) f[j] = (_Float16)p[j];
            w2f[ks][nt] = f;
        }
    }
    // ---- B-fragments for layer 3: B[k=o2][n=o3] = W3[o3][o2], o3 = nt*16+col, o2 = quad*8+32ks+j
    f16x8 w3f[4][4];
    #pragma unroll
    for (int ks=0; ks<4; ks++){
        #pragma unroll
        for (int nt=0; nt<4; nt++){
            const float* p = W3 + (nt*16+col)*128 + quad*8 + 32*ks;
            f16x8 f;
            #pragma unroll
            for (int j=0;j<8;j++) f[j] = (_Float16)p[j];
            w3f[ks][nt] = f;
        }
    }
    // ---- layer-1 weights, packed fp16 pairs for this lane's A-frag channels
    // lane's channels: c = quad*8 + (0..7) + 32*ks
    f16x2 w1p[2][4][3];
    f16x2 b1p[2][4];
    #pragma unroll
    for (int ks=0; ks<2; ks++){
        #pragma unroll
        for (int j2=0; j2<4; j2++){
            int c0 = quad*8 + 2*j2 + 32*ks;
            #pragma unroll
            for (int i=0;i<3;i++){
                f16x2 w; w[0] = (_Float16)W1[c0*3+i]; w[1] = (_Float16)W1[(c0+1)*3+i];
                w1p[ks][j2][i] = w;
            }
            f16x2 bb; bb[0] = (_Float16)b1[c0]; bb[1] = (_Float16)b1[c0+1];
            b1p[ks][j2] = bb;
        }
    }
    __syncthreads();

    f32x4 hm[4];
    #pragma unroll
    for (int nt=0;nt<4;nt++){
        hm[nt][0] = -__builtin_inff(); hm[nt][1] = -__builtin_inff();
        hm[nt][2] = -__builtin_inff(); hm[nt][3] = -__builtin_inff();
    }

    const float* xb = x + (size_t)b*3*LL;
    const int wave_off = wave*16*136;

    #pragma unroll 1
    for (int it=0; it<LL/64; it++){
        const int pos = it*64 + wave*16 + col;
        const float x0 = xb[pos], x1 = xb[LL+pos], x2 = xb[2*LL+pos];
        f16x2 xh0; xh0[0] = (_Float16)x0; xh0[1] = xh0[0];
        f16x2 xh1; xh1[0] = (_Float16)x1; xh1[1] = xh1[0];
        f16x2 xh2; xh2[0] = (_Float16)x2; xh2[1] = xh2[0];

        // ---- layer 1 directly into A-fragments: a2[ks][j] = h1[pos=col][c=quad*8+j+32ks]
        f16x8 a2[2];
        #pragma unroll
        for (int ks=0; ks<2; ks++){
            f16x8 a;
            #pragma unroll
            for (int j2=0; j2<4; j2++){
                f16x2 v = b1p[ks][j2];
                v += w1p[ks][j2][0]*xh0;
                v += w1p[ks][j2][1]*xh1;
                v += w1p[ks][j2][2]*xh2;
                _Float16 e0 = v[0], e1 = v[1];
                e0 = (e0 > (_Float16)0) ? e0 : e0*(_Float16)0.001f;
                e1 = (e1 > (_Float16)0) ? e1 : e1*(_Float16)0.001f;
                a[2*j2]   = e0;
                a[2*j2+1] = e1;
            }
            a2[ks] = a;
        }

        // ---- layer 2: 16 MFMAs, acc init = b2 broadcast per channel
        f32x4 acc2[8];
        #pragma unroll
        for (int nt=0; nt<8; nt++){
            float bb = ldsB2[nt*16+col];
            acc2[nt][0]=bb; acc2[nt][1]=bb; acc2[nt][2]=bb; acc2[nt][3]=bb;
        }
        #pragma unroll
        for (int nt=0; nt<8; nt++){
            acc2[nt] = __builtin_amdgcn_mfma_f32_16x16x32_f16(a2[0], w2f[0][nt], acc2[nt], 0,0,0);
            acc2[nt] = __builtin_amdgcn_mfma_f32_16x16x32_f16(a2[1], w2f[1][nt], acc2[nt], 0,0,0);
        }

        // ---- leaky + C-layout -> LDS [pos][ch] as fp16
        #pragma unroll
        for (int nt=0; nt<8; nt++){
            #pragma unroll
            for (int j=0; j<4; j++){
                float v = leakyf(acc2[nt][j]);
                h2lds[wave_off + (quad*4+j)*136 + nt*16+col] = (_Float16)v;
            }
        }

        // ---- layer 3: read A-frags from LDS, 16 MFMAs (bias b3 folded in after max)
        f32x4 acc3[4];
        #pragma unroll
        for (int nt=0; nt<4; nt++){ acc3[nt][0]=0.f; acc3[nt][1]=0.f; acc3[nt][2]=0.f; acc3[nt][3]=0.f; }
        #pragma unroll
        for (int ks=0; ks<4; ks++){
            f16x8 a3 = *(const f16x8*)&h2lds[wave_off + col*136 + quad*8 + 32*ks];
            #pragma unroll
            for (int nt=0; nt<4; nt++)
                acc3[nt] = __builtin_amdgcn_mfma_f32_16x16x32_f16(a3, w3f[ks][nt], acc3[nt], 0,0,0);
        }
        #pragma unroll
        for (int nt=0; nt<4; nt++){
            hm[nt][0] = fmaxf(hm[nt][0], acc3[nt][0]);
            hm[nt][1] = fmaxf(hm[nt][1], acc3[nt][1]);
            hm[nt][2] = fmaxf(hm[nt][2], acc3[nt][2]);
            hm[nt][3] = fmaxf(hm[nt][3], acc3[nt][3]);
        }
    }

    // ---- reduce max over positions: within-lane rows, then quads, then waves
    #pragma unroll
    for (int nt=0; nt<4; nt++){
        float v = fmaxf(fmaxf(hm[nt][0], hm[nt][1]), fmaxf(hm[nt][2], hm[nt][3]));
        v = fmaxf(v, __shfl_xor(v, 16, 64));
        v = fmaxf(v, __shfl_xor(v, 32, 64));
        if (quad == 0) red[wave][nt*16 + col] = v;
    }
    __syncthreads();
    if (t < 64){
        float v = fmaxf(fmaxf(red[0][t], red[1][t]), fmaxf(red[2][t], red[3][t]));
        z_out[(size_t)b*64 + t] = v + b3[t];
    }
}

// ---------------- VQ: nearest codebook entry per batch row ----------------
__global__ __launch_bounds__(256, 1) void vq_kernel(
    const float* __restrict__ z, const float* __restrict__ cb, int* __restrict__ idx_out)
{
    const int b = blockIdx.x;
    const int t = threadIdx.x;
    float zr[64];
    #pragma unroll
    for (int d=0; d<64; d+=4){
        float4 zv = *(const float4*)(z + (size_t)b*64 + d);
        zr[d]=zv.x; zr[d+1]=zv.y; zr[d+2]=zv.z; zr[d+3]=zv.w;
    }
    float best = __builtin_inff(); int bidx = 0;
    for (int k = t; k < KK; k += 256){
        const float4* c4 = (const float4*)(cb + (size_t)k*64);
        float d0=0.f,d1=0.f,d2=0.f,d3=0.f;
        #pragma unroll
        for (int q=0;q<16;q++){
            float4 cv = c4[q];
            float t0 = zr[q*4+0]-cv.x; d0 = fmaf(t0,t0,d0);
            float t1 = zr[q*4+1]-cv.y; d1 = fmaf(t1,t1,d1);
            float t2 = zr[q*4+2]-cv.z; d2 = fmaf(t2,t2,d2);
            float t3 = zr[q*4+3]-cv.w; d3 = fmaf(t3,t3,d3);
        }
        float dist = (d0+d1)+(d2+d3);
        if (dist < best){ best = dist; bidx = k; }
    }
    __shared__ float sb[256];
    __shared__ int   si[256];
    sb[t]=best; si[t]=bidx;
    __syncthreads();
    for (int s=128; s>0; s>>=1){
        if (t < s){
            float ob = sb[t+s]; int oi = si[t+s];
            if (ob < sb[t] || (ob == sb[t] && oi < si[t])){ sb[t]=ob; si[t]=oi; }
        }
        __syncthreads();
    }
    if (t==0) idx_out[b] = si[0];
}

// ---------------- decoder (64->128->64->3) + per-b loss partial ----------------
__global__ __launch_bounds__(128, 1) void decoder_kernel(
    const float* __restrict__ z, const int* __restrict__ idx,
    const float* __restrict__ cb,
    const float* __restrict__ U1, const float* __restrict__ c1,
    const float* __restrict__ U2, const float* __restrict__ c2,
    const float* __restrict__ U3, const float* __restrict__ c3,
    float* __restrict__ xrec, float* __restrict__ loss_part)
{
    const int b = blockIdx.x;
    const int t = threadIdx.x;
    __shared__ float zst[64];
    __shared__ float g1[128];
    __shared__ float g2[64];
    const int kk = idx[b];
    if (t < 64){
        float zv = z[(size_t)b*64 + t];
        float zq = cb[(size_t)kk*64 + t];
        float diff = zq - zv;
        zst[t] = zv + diff;                 // straight-through forward value
        float p = diff*diff;
        #pragma unroll
        for (int s=32;s>0;s>>=1) p += __shfl_xor(p, s, 64);
        if (t==0) loss_part[b] = p;
    }
    __syncthreads();
    {
        float v = c1[t];
        #pragma unroll
        for (int d=0; d<64; d++) v = fmaf(zst[d], U1[d*128+t], v);
        g1[t] = leakyf(v);
    }
    __syncthreads();
    if (t < 64){
        float v = c2[t];
        #pragma unroll
        for (int j=0;j<128;j++) v = fmaf(g1[j], U2[j*64+t], v);
        g2[t] = leakyf(v);
    }
    __syncthreads();
    if (t < 3){
        float v = c3[t];
        #pragma unroll
        for (int j=0;j<64;j++) v = fmaf(g2[j], U3[j*3+t], v);
        xrec[(size_t)b*3 + t] = v;
    }
}

__global__ __launch_bounds__(256, 1) void loss_kernel(
    const float* __restrict__ loss_part, float* __restrict__ out)
{
    const int t = threadIdx.x;
    float s = 0.f;
    for (int i=t;i<BB;i+=256) s += loss_part[i];
    #pragma unroll
    for (int sh=32;sh>0;sh>>=1) s += __shfl_xor(s, sh, 64);
    __shared__ float w[4];
    if ((t&63)==0) w[t>>6] = s;
    __syncthreads();
    if (t==0) out[0] = (w[0]+w[1]+w[2]+w[3]) * (1.25f / 65536.0f);
}

extern "C" void kernel_launch(void* const* d_in, const int* in_sizes, int n_in,
                              void* d_out, int out_size, void* d_ws, size_t ws_size,
                              hipStream_t stream)
{
    const float* x  = (const float*)d_in[0];
    const float* W1 = (const float*)d_in[1];
    const float* b1 = (const float*)d_in[2];
    const float* W2 = (const float*)d_in[3];
    const float* b2 = (const float*)d_in[4];
    const float* W3 = (const float*)d_in[5];
    const float* b3 = (const float*)d_in[6];
    const float* cb = (const float*)d_in[7];
    const float* U1 = (const float*)d_in[8];
    const float* c1 = (const float*)d_in[9];
    const float* U2 = (const float*)d_in[10];
    const float* c2 = (const float*)d_in[11];
    const float* U3 = (const float*)d_in[12];
    const float* c3 = (const float*)d_in[13];

    float* out  = (float*)d_out;
    float* xrec = out;              // [1024*3]
    float* loss = out + 3072;       // [1]
    float* z    = out + 3073;       // [1024*64]

    char*  ws  = (char*)d_ws;
    int*   idx = (int*)ws;                      // 1024 i32
    float* lp  = (float*)(ws + 4096);           // 1024 f32

    hipLaunchKernelGGL(encoder_mfma, dim3(BB), dim3(256), 0, stream,
                       x, W1, b1, W2, b2, W3, b3, z);
    hipLaunchKernelGGL(vq_kernel, dim3(BB), dim3(256), 0, stream, z, cb, idx);
    hipLaunchKernelGGL(decoder_kernel, dim3(BB), dim3(128), 0, stream,
                       z, idx, cb, U1, c1, U2, c2, U3, c3, xrec, lp);
    hipLaunchKernelGGL(loss_kernel, dim3(1), dim3(256), 0, stream, lp, loss);
}

// Round 3
// 247.646 us; speedup vs baseline: 14.8180x; 1.9056x over previous
//
#include <hip/hip_runtime.h>
#include <hip/hip_bf16.h>

#define BB 1024
#define LL 2048
#define KK 8192

typedef _Float16 f16x8 __attribute__((ext_vector_type(8)));
typedef _Float16 f16x2 __attribute__((ext_vector_type(2)));
typedef float    f32x4 __attribute__((ext_vector_type(4)));

__device__ __forceinline__ float leakyf(float v){ return fmaxf(v, 0.001f*v); }

// ---------------- encoder: fused conv1x1 (3->64->128->64) + global max over L ----------------
// grid = 1024 (one block per b), 256 threads = 4 waves; wave does 16 positions/iter, 32 iters.
// W2/W3 live in registers as MFMA B-fragments. Layer-2 done in two 4-nt phases to keep
// peak VGPR < 256 (no scratch spills). x loads prefetched one iter ahead.
__global__ __launch_bounds__(256, 2) void encoder_mfma(
    const float* __restrict__ x,
    const float* __restrict__ W1, const float* __restrict__ b1,
    const float* __restrict__ W2, const float* __restrict__ b2,
    const float* __restrict__ W3, const float* __restrict__ b3,
    float* __restrict__ z_out, _Float16* __restrict__ zh_out)
{
    const int b    = blockIdx.x;
    const int t    = threadIdx.x;
    const int wave = t >> 6;
    const int lane = t & 63;
    const int col  = lane & 15;
    const int quad = lane >> 4;

    __shared__ __align__(16) _Float16 h2lds[4*16*136];  // 272B row stride
    __shared__ float red[4][64];

    // B-frags layer 2: B[k=c][n=o2], o2 = nt*16+col, c = quad*8+32ks+j
    f16x8 w2f[2][8];
    #pragma unroll
    for (int ks=0; ks<2; ks++){
        #pragma unroll
        for (int nt=0; nt<8; nt++){
            const float* p = W2 + (nt*16+col)*64 + quad*8 + 32*ks;
            f16x8 f;
            #pragma unroll
            for (int j=0;j<8;j++) f[j] = (_Float16)p[j];
            w2f[ks][nt] = f;
        }
    }
    // B-frags layer 3: B[k=o2][n=o3]
    f16x8 w3f[4][4];
    #pragma unroll
    for (int ks=0; ks<4; ks++){
        #pragma unroll
        for (int nt=0; nt<4; nt++){
            const float* p = W3 + (nt*16+col)*128 + quad*8 + 32*ks;
            f16x8 f;
            #pragma unroll
            for (int j=0;j<8;j++) f[j] = (_Float16)p[j];
            w3f[ks][nt] = f;
        }
    }
    // layer-1 weights packed per-lane
    f16x2 w1p[2][4][3];
    f16x2 b1p[2][4];
    #pragma unroll
    for (int ks=0; ks<2; ks++){
        #pragma unroll
        for (int j2=0; j2<4; j2++){
            int c0 = quad*8 + 2*j2 + 32*ks;
            #pragma unroll
            for (int i=0;i<3;i++){
                f16x2 w; w[0] = (_Float16)W1[c0*3+i]; w[1] = (_Float16)W1[(c0+1)*3+i];
                w1p[ks][j2][i] = w;
            }
            f16x2 bb; bb[0] = (_Float16)b1[c0]; bb[1] = (_Float16)b1[c0+1];
            b1p[ks][j2] = bb;
        }
    }
    // b2 per-lane (channel nt*16+col)
    float bb2[8];
    #pragma unroll
    for (int nt=0; nt<8; nt++) bb2[nt] = b2[nt*16+col];

    f32x4 hm[4];
    #pragma unroll
    for (int nt=0;nt<4;nt++){
        hm[nt][0] = -__builtin_inff(); hm[nt][1] = -__builtin_inff();
        hm[nt][2] = -__builtin_inff(); hm[nt][3] = -__builtin_inff();
    }

    const float* xb = x + (size_t)b*3*LL;
    const int wave_off = wave*16*136;
    const int pbase = wave*16 + col;

    float x0n = xb[pbase], x1n = xb[LL+pbase], x2n = xb[2*LL+pbase];

    #pragma unroll 1
    for (int it=0; it<LL/64; it++){
        const float x0 = x0n, x1 = x1n, x2 = x2n;
        {   // prefetch next iter's x
            int itn = it+1 < 32 ? it+1 : 31;
            int pn = itn*64 + pbase;
            x0n = xb[pn]; x1n = xb[LL+pn]; x2n = xb[2*LL+pn];
        }
        f16x2 xh0; xh0[0] = (_Float16)x0; xh0[1] = xh0[0];
        f16x2 xh1; xh1[0] = (_Float16)x1; xh1[1] = xh1[0];
        f16x2 xh2; xh2[0] = (_Float16)x2; xh2[1] = xh2[0];

        // layer 1 -> A-frags
        f16x8 a2[2];
        #pragma unroll
        for (int ks=0; ks<2; ks++){
            f16x8 a;
            #pragma unroll
            for (int j2=0; j2<4; j2++){
                f16x2 v = b1p[ks][j2];
                v += w1p[ks][j2][0]*xh0;
                v += w1p[ks][j2][1]*xh1;
                v += w1p[ks][j2][2]*xh2;
                _Float16 e0 = v[0], e1 = v[1];
                e0 = (e0 > (_Float16)0) ? e0 : e0*(_Float16)0.001f;
                e1 = (e1 > (_Float16)0) ? e1 : e1*(_Float16)0.001f;
                a[2*j2]   = e0;
                a[2*j2+1] = e1;
            }
            a2[ks] = a;
        }

        // layer 2 in two phases of 4 output-tiles (keeps acc live range at 16 VGPRs)
        #pragma unroll
        for (int ph=0; ph<2; ph++){
            f32x4 acc2[4];
            #pragma unroll
            for (int n=0; n<4; n++){
                float bb = bb2[ph*4+n];
                acc2[n][0]=bb; acc2[n][1]=bb; acc2[n][2]=bb; acc2[n][3]=bb;
            }
            #pragma unroll
            for (int n=0; n<4; n++){
                acc2[n] = __builtin_amdgcn_mfma_f32_16x16x32_f16(a2[0], w2f[0][ph*4+n], acc2[n], 0,0,0);
                acc2[n] = __builtin_amdgcn_mfma_f32_16x16x32_f16(a2[1], w2f[1][ph*4+n], acc2[n], 0,0,0);
            }
            #pragma unroll
            for (int n=0; n<4; n++){
                #pragma unroll
                for (int j=0; j<4; j++){
                    float v = leakyf(acc2[n][j]);
                    h2lds[wave_off + (quad*4+j)*136 + (ph*4+n)*16+col] = (_Float16)v;
                }
            }
        }

        // layer 3
        f32x4 acc3[4];
        #pragma unroll
        for (int nt=0; nt<4; nt++){ acc3[nt][0]=0.f; acc3[nt][1]=0.f; acc3[nt][2]=0.f; acc3[nt][3]=0.f; }
        #pragma unroll
        for (int ks=0; ks<4; ks++){
            f16x8 a3 = *(const f16x8*)&h2lds[wave_off + col*136 + quad*8 + 32*ks];
            #pragma unroll
            for (int nt=0; nt<4; nt++)
                acc3[nt] = __builtin_amdgcn_mfma_f32_16x16x32_f16(a3, w3f[ks][nt], acc3[nt], 0,0,0);
        }
        #pragma unroll
        for (int nt=0; nt<4; nt++){
            hm[nt][0] = fmaxf(hm[nt][0], acc3[nt][0]);
            hm[nt][1] = fmaxf(hm[nt][1], acc3[nt][1]);
            hm[nt][2] = fmaxf(hm[nt][2], acc3[nt][2]);
            hm[nt][3] = fmaxf(hm[nt][3], acc3[nt][3]);
        }
    }

    #pragma unroll
    for (int nt=0; nt<4; nt++){
        float v = fmaxf(fmaxf(hm[nt][0], hm[nt][1]), fmaxf(hm[nt][2], hm[nt][3]));
        v = fmaxf(v, __shfl_xor(v, 16, 64));
        v = fmaxf(v, __shfl_xor(v, 32, 64));
        if (quad == 0) red[wave][nt*16 + col] = v;
    }
    __syncthreads();
    if (t < 64){
        float v = fmaxf(fmaxf(red[0][t], red[1][t]), fmaxf(red[2][t], red[3][t])) + b3[t];
        z_out[(size_t)b*64 + t] = v;
        zh_out[(size_t)b*64 + t] = (_Float16)v;
    }
}

// ---------------- VQ prep: codebook -> fp16 + ||c||^2 ----------------
__global__ __launch_bounds__(256, 4) void vq_prep(
    const float* __restrict__ cb, _Float16* __restrict__ cbh, float* __restrict__ cnorm)
{
    const int t = threadIdx.x;
    const int e = blockIdx.x*4 + (t>>6);
    const int d = t & 63;
    float v = cb[(size_t)e*64 + d];
    cbh[(size_t)e*64 + d] = (_Float16)v;
    float p = v*v;
    #pragma unroll
    for (int s=32;s>0;s>>=1) p += __shfl_xor(p, s, 64);
    if (d==0) cnorm[e] = p;
}

// ---------------- VQ GEMM: argmin_k (||c||^2 - 2 z.c) via fp16 MFMA ----------------
// grid 512: rb = blockIdx>>5 (16 row-blocks of 64), ns = blockIdx&31 (32 splits of 256 entries).
// Wave handles 16 rows x 256 entries (16 n-tiles).
__global__ __launch_bounds__(256, 2) void vq_mfma(
    const _Float16* __restrict__ zh, const _Float16* __restrict__ cbh,
    const float* __restrict__ cnorm,
    float* __restrict__ pval, int* __restrict__ pidx)
{
    const int t    = threadIdx.x;
    const int wave = t >> 6;
    const int lane = t & 63;
    const int col  = lane & 15;
    const int quad = lane >> 4;
    const int rb   = blockIdx.x >> 5;
    const int ns   = blockIdx.x & 31;
    const int rowbase = rb*64 + wave*16;

    // A-frags: A[m=col][k=quad*8+32ks+j] = z[rowbase+col][k]
    f16x8 az[2];
    az[0] = *(const f16x8*)&zh[(size_t)(rowbase+col)*64 + quad*8];
    az[1] = *(const f16x8*)&zh[(size_t)(rowbase+col)*64 + quad*8 + 32];

    float best[4] = {__builtin_inff(),__builtin_inff(),__builtin_inff(),__builtin_inff()};
    int   bidx[4] = {0,0,0,0};

    int e = ns*256;
    f16x8 bf0 = *(const f16x8*)&cbh[(size_t)(e+col)*64 + quad*8];
    f16x8 bf1 = *(const f16x8*)&cbh[(size_t)(e+col)*64 + quad*8 + 32];
    float cn  = cnorm[e+col];

    #pragma unroll 1
    for (int nt=0; nt<16; nt++){
        f16x8 c0 = bf0, c1 = bf1;
        float cnc = cn;
        int ec = e;
        if (nt < 15){
            e += 16;
            bf0 = *(const f16x8*)&cbh[(size_t)(e+col)*64 + quad*8];
            bf1 = *(const f16x8*)&cbh[(size_t)(e+col)*64 + quad*8 + 32];
            cn  = cnorm[e+col];
        }
        f32x4 acc; acc[0]=0.f; acc[1]=0.f; acc[2]=0.f; acc[3]=0.f;
        acc = __builtin_amdgcn_mfma_f32_16x16x32_f16(az[0], c0, acc, 0,0,0);
        acc = __builtin_amdgcn_mfma_f32_16x16x32_f16(az[1], c1, acc, 0,0,0);
        int myidx = ec + col;
        #pragma unroll
        for (int r=0; r<4; r++){
            float d = fmaf(-2.0f, acc[r], cnc);
            if (d < best[r]){ best[r] = d; bidx[r] = myidx; }
        }
    }

    // reduce across the 16 cols (lanes within the same quad group)
    #pragma unroll
    for (int r=0; r<4; r++){
        float v = best[r]; int i = bidx[r];
        #pragma unroll
        for (int s=1; s<16; s<<=1){
            float ov = __shfl_xor(v, s, 64);
            int   oi = __shfl_xor(i, s, 64);
            if (ov < v || (ov == v && oi < i)){ v = ov; i = oi; }
        }
        if (col == 0){
            int row = rowbase + quad*4 + r;
            pval[row*32 + ns] = v;
            pidx[row*32 + ns] = i;
        }
    }
}

__global__ __launch_bounds__(256, 4) void vq_merge(
    const float* __restrict__ pval, const int* __restrict__ pidx, int* __restrict__ idx_out)
{
    const int row = blockIdx.x*256 + threadIdx.x;
    float best = __builtin_inff(); int bi = 0;
    #pragma unroll 4
    for (int s=0; s<32; s++){
        float v = pval[row*32 + s]; int i = pidx[row*32 + s];
        if (v < best || (v == best && i < bi)){ best = v; bi = i; }
    }
    idx_out[row] = bi;
}

// ---------------- decoder (64->128->64->3) + per-b loss partial ----------------
__global__ __launch_bounds__(128, 1) void decoder_kernel(
    const float* __restrict__ z, const int* __restrict__ idx,
    const float* __restrict__ cb,
    const float* __restrict__ U1, const float* __restrict__ c1,
    const float* __restrict__ U2, const float* __restrict__ c2,
    const float* __restrict__ U3, const float* __restrict__ c3,
    float* __restrict__ xrec, float* __restrict__ loss_part)
{
    const int b = blockIdx.x;
    const int t = threadIdx.x;
    __shared__ float zst[64];
    __shared__ float g1[128];
    __shared__ float g2[64];
    const int kk = idx[b];
    if (t < 64){
        float zv = z[(size_t)b*64 + t];
        float zq = cb[(size_t)kk*64 + t];
        float diff = zq - zv;
        zst[t] = zv + diff;
        float p = diff*diff;
        #pragma unroll
        for (int s=32;s>0;s>>=1) p += __shfl_xor(p, s, 64);
        if (t==0) loss_part[b] = p;
    }
    __syncthreads();
    {
        float v = c1[t];
        #pragma unroll
        for (int d=0; d<64; d++) v = fmaf(zst[d], U1[d*128+t], v);
        g1[t] = leakyf(v);
    }
    __syncthreads();
    if (t < 64){
        float v = c2[t];
        #pragma unroll
        for (int j=0;j<128;j++) v = fmaf(g1[j], U2[j*64+t], v);
        g2[t] = leakyf(v);
    }
    __syncthreads();
    if (t < 3){
        float v = c3[t];
        #pragma unroll
        for (int j=0;j<64;j++) v = fmaf(g2[j], U3[j*3+t], v);
        xrec[(size_t)b*3 + t] = v;
    }
}

__global__ __launch_bounds__(256, 1) void loss_kernel(
    const float* __restrict__ loss_part, float* __restrict__ out)
{
    const int t = threadIdx.x;
    float s = 0.f;
    for (int i=t;i<BB;i+=256) s += loss_part[i];
    #pragma unroll
    for (int sh=32;sh>0;sh>>=1) s += __shfl_xor(s, sh, 64);
    __shared__ float w[4];
    if ((t&63)==0) w[t>>6] = s;
    __syncthreads();
    if (t==0) out[0] = (w[0]+w[1]+w[2]+w[3]) * (1.25f / 65536.0f);
}

extern "C" void kernel_launch(void* const* d_in, const int* in_sizes, int n_in,
                              void* d_out, int out_size, void* d_ws, size_t ws_size,
                              hipStream_t stream)
{
    const float* x  = (const float*)d_in[0];
    const float* W1 = (const float*)d_in[1];
    const float* b1 = (const float*)d_in[2];
    const float* W2 = (const float*)d_in[3];
    const float* b2 = (const float*)d_in[4];
    const float* W3 = (const float*)d_in[5];
    const float* b3 = (const float*)d_in[6];
    const float* cb = (const float*)d_in[7];
    const float* U1 = (const float*)d_in[8];
    const float* c1 = (const float*)d_in[9];
    const float* U2 = (const float*)d_in[10];
    const float* c2 = (const float*)d_in[11];
    const float* U3 = (const float*)d_in[12];
    const float* c3 = (const float*)d_in[13];

    float* out  = (float*)d_out;
    float* xrec = out;              // [1024*3]
    float* loss = out + 3072;       // [1]
    float* z    = out + 3073;       // [1024*64]

    char* ws = (char*)d_ws;
    int*      idx   = (int*)ws;                         // 4 KB
    float*    lp    = (float*)(ws + 4096);              // 4 KB
    _Float16* zh    = (_Float16*)(ws + 8192);           // 128 KB
    float*    cnorm = (float*)(ws + 139264);            // 32 KB
    float*    pval  = (float*)(ws + 172032);            // 128 KB
    int*      pidx  = (int*)(ws + 303104);              // 128 KB
    _Float16* cbh   = (_Float16*)(ws + 434176);         // 1 MB

    hipLaunchKernelGGL(encoder_mfma, dim3(BB), dim3(256), 0, stream,
                       x, W1, b1, W2, b2, W3, b3, z, zh);
    hipLaunchKernelGGL(vq_prep, dim3(KK/4), dim3(256), 0, stream, cb, cbh, cnorm);
    hipLaunchKernelGGL(vq_mfma, dim3(512), dim3(256), 0, stream, zh, cbh, cnorm, pval, pidx);
    hipLaunchKernelGGL(vq_merge, dim3(4), dim3(256), 0, stream, pval, pidx, idx);
    hipLaunchKernelGGL(decoder_kernel, dim3(BB), dim3(128), 0, stream,
                       z, idx, cb, U1, c1, U2, c2, U3, c3, xrec, lp);
    hipLaunchKernelGGL(loss_kernel, dim3(1), dim3(256), 0, stream, lp, loss);
}

// Round 5
// 226.167 us; speedup vs baseline: 16.2252x; 1.0950x over previous
//
#include <hip/hip_runtime.h>
#include <hip/hip_bf16.h>

#define BB 1024
#define LL 2048
#define KK 8192

typedef _Float16 f16x8 __attribute__((ext_vector_type(8)));
typedef _Float16 f16x4 __attribute__((ext_vector_type(4)));
typedef _Float16 f16x2 __attribute__((ext_vector_type(2)));
typedef float    f32x4 __attribute__((ext_vector_type(4)));

__device__ __forceinline__ float leakyf(float v){ return fmaxf(v, 0.001f*v); }
__device__ __forceinline__ f16x2 pkrtz(float a, float b){
    return __builtin_bit_cast(f16x2, __builtin_amdgcn_cvt_pkrtz(a, b));
}

// ---------------- encoder: fused conv1x1 (3->64->128->64) + global max over L ----------------
// One block per b, 4 waves; wave = 16 positions/iter, 32 iters. W2/W3 register-stationary
// MFMA fragments. h2 C->A transform via wave-private LDS with quad-XOR bank swizzle.
// Zero-C MFMA chaining (no acc-init movs); packed-f16 epilogue (cvt_pkrtz + pk bias/leaky).
__global__ __launch_bounds__(256, 2) void encoder_mfma(
    const float* __restrict__ x,
    const float* __restrict__ W1, const float* __restrict__ b1,
    const float* __restrict__ W2, const float* __restrict__ b2,
    const float* __restrict__ W3, const float* __restrict__ b3,
    float* __restrict__ z_out, _Float16* __restrict__ zh_out)
{
    const int b    = blockIdx.x;
    const int t    = threadIdx.x;
    const int wave = t >> 6;
    const int lane = t & 63;
    const int col  = lane & 15;
    const int quad = lane >> 4;

    __shared__ __align__(16) _Float16 h2lds[4*16*136];  // 272B row stride, quad-XOR swizzled cols
    __shared__ float red[4][64];

    // B-frags layer 2: B[k=c][n=o2], o2 = nt*16+col, c = quad*8+32ks+j
    f16x8 w2f[2][8];
    #pragma unroll
    for (int ks=0; ks<2; ks++){
        #pragma unroll
        for (int nt=0; nt<8; nt++){
            const float* p = W2 + (nt*16+col)*64 + quad*8 + 32*ks;
            f16x8 f;
            #pragma unroll
            for (int j=0;j<8;j++) f[j] = (_Float16)p[j];
            w2f[ks][nt] = f;
        }
    }
    // B-frags layer 3: B[k=o2][n=o3]
    f16x8 w3f[4][4];
    #pragma unroll
    for (int ks=0; ks<4; ks++){
        #pragma unroll
        for (int nt=0; nt<4; nt++){
            const float* p = W3 + (nt*16+col)*128 + quad*8 + 32*ks;
            f16x8 f;
            #pragma unroll
            for (int j=0;j<8;j++) f[j] = (_Float16)p[j];
            w3f[ks][nt] = f;
        }
    }
    // layer-1 weights packed per-lane (channels quad*8 + 2*j2{+1} + 32ks)
    f16x2 w1p[2][4][3];
    f16x2 b1p[2][4];
    #pragma unroll
    for (int ks=0; ks<2; ks++){
        #pragma unroll
        for (int j2=0; j2<4; j2++){
            int c0 = quad*8 + 2*j2 + 32*ks;
            #pragma unroll
            for (int i=0;i<3;i++){
                f16x2 w; w[0] = (_Float16)W1[c0*3+i]; w[1] = (_Float16)W1[(c0+1)*3+i];
                w1p[ks][j2][i] = w;
            }
            f16x2 bb; bb[0] = (_Float16)b1[c0]; bb[1] = (_Float16)b1[c0+1];
            b1p[ks][j2] = bb;
        }
    }
    // b2 as packed pairs (same channel both halves; pairs are position-rows)
    f16x2 b2p[8];
    #pragma unroll
    for (int nt=0; nt<8; nt++){
        _Float16 bv = (_Float16)b2[nt*16+col];
        f16x2 p; p[0]=bv; p[1]=bv; b2p[nt]=p;
    }

    f16x2 k001; k001[0] = (_Float16)0.001f; k001[1] = (_Float16)0.001f;
    f32x4 zc; zc[0]=0.f; zc[1]=0.f; zc[2]=0.f; zc[3]=0.f;

    f32x4 hm[4];
    #pragma unroll
    for (int nt=0;nt<4;nt++){
        hm[nt][0] = -__builtin_inff(); hm[nt][1] = -__builtin_inff();
        hm[nt][2] = -__builtin_inff(); hm[nt][3] = -__builtin_inff();
    }

    const float* xb = x + (size_t)b*3*LL;
    const int wave_off = wave*2176;          // 16*136
    const int pbase = wave*16 + col;
    const int rswz  = (col >> 2) << 4;       // read-side row-quad XOR

    float x0n = xb[pbase], x1n = xb[LL+pbase], x2n = xb[2*LL+pbase];

    #pragma unroll 1
    for (int it=0; it<LL/64; it++){
        const float x0 = x0n, x1 = x1n, x2 = x2n;
        {   // prefetch next iter's x
            int itn = it+1 < 32 ? it+1 : 31;
            int pn = itn*64 + pbase;
            x0n = xb[pn]; x1n = xb[LL+pn]; x2n = xb[2*LL+pn];
        }
        f16x2 xh0; xh0[0] = (_Float16)x0; xh0[1] = xh0[0];
        f16x2 xh1; xh1[0] = (_Float16)x1; xh1[1] = xh1[0];
        f16x2 xh2; xh2[0] = (_Float16)x2; xh2[1] = xh2[0];

        // layer 1 -> A-frags (packed leaky)
        f16x8 a2[2];
        #pragma unroll
        for (int ks=0; ks<2; ks++){
            f16x8 a;
            #pragma unroll
            for (int j2=0; j2<4; j2++){
                f16x2 v = b1p[ks][j2];
                v += w1p[ks][j2][0]*xh0;
                v += w1p[ks][j2][1]*xh1;
                v += w1p[ks][j2][2]*xh2;
                v = __builtin_elementwise_max(v, v*k001);
                a[2*j2]   = v[0];
                a[2*j2+1] = v[1];
            }
            a2[ks] = a;
        }

        // layer 2: zero-C chained MFMAs, packed epilogue, swizzled b16 stores
        #pragma unroll
        for (int ph=0; ph<2; ph++){
            #pragma unroll
            for (int n=0; n<4; n++){
                const int nt = ph*4 + n;
                f32x4 acc = __builtin_amdgcn_mfma_f32_16x16x32_f16(a2[0], w2f[0][nt], zc, 0,0,0);
                acc = __builtin_amdgcn_mfma_f32_16x16x32_f16(a2[1], w2f[1][nt], acc, 0,0,0);
                f16x2 p01 = pkrtz(acc[0], acc[1]);
                f16x2 p23 = pkrtz(acc[2], acc[3]);
                p01 += b2p[nt];  p23 += b2p[nt];
                p01 = __builtin_elementwise_max(p01, p01*k001);
                p23 = __builtin_elementwise_max(p23, p23*k001);
                _Float16* wp = &h2lds[wave_off + quad*4*136 + ((nt ^ quad)<<4) + col];
                wp[0]     = p01[0];
                wp[136]   = p01[1];
                wp[272]   = p23[0];
                wp[408]   = p23[1];
            }
        }

        // layer 3: swizzled b128 reads, zero-C chained
        f16x8 a30 = *(const f16x8*)&h2lds[wave_off + col*136 + (( 0 + quad*8) ^ rswz)];
        f16x8 a31 = *(const f16x8*)&h2lds[wave_off + col*136 + ((32 + quad*8) ^ rswz)];
        f16x8 a32 = *(const f16x8*)&h2lds[wave_off + col*136 + ((64 + quad*8) ^ rswz)];
        f16x8 a33 = *(const f16x8*)&h2lds[wave_off + col*136 + ((96 + quad*8) ^ rswz)];
        #pragma unroll
        for (int nt=0; nt<4; nt++){
            f32x4 acc = __builtin_amdgcn_mfma_f32_16x16x32_f16(a30, w3f[0][nt], zc, 0,0,0);
            acc = __builtin_amdgcn_mfma_f32_16x16x32_f16(a31, w3f[1][nt], acc, 0,0,0);
            acc = __builtin_amdgcn_mfma_f32_16x16x32_f16(a32, w3f[2][nt], acc, 0,0,0);
            acc = __builtin_amdgcn_mfma_f32_16x16x32_f16(a33, w3f[3][nt], acc, 0,0,0);
            hm[nt][0] = fmaxf(hm[nt][0], acc[0]);
            hm[nt][1] = fmaxf(hm[nt][1], acc[1]);
            hm[nt][2] = fmaxf(hm[nt][2], acc[2]);
            hm[nt][3] = fmaxf(hm[nt][3], acc[3]);
        }
    }

    #pragma unroll
    for (int nt=0; nt<4; nt++){
        float v = fmaxf(fmaxf(hm[nt][0], hm[nt][1]), fmaxf(hm[nt][2], hm[nt][3]));
        v = fmaxf(v, __shfl_xor(v, 16, 64));
        v = fmaxf(v, __shfl_xor(v, 32, 64));
        if (quad == 0) red[wave][nt*16 + col] = v;
    }
    __syncthreads();
    if (t < 64){
        float v = fmaxf(fmaxf(red[0][t], red[1][t]), fmaxf(red[2][t], red[3][t])) + b3[t];
        z_out[(size_t)b*64 + t] = v;
        zh_out[(size_t)b*64 + t] = (_Float16)v;
    }
}

// ---------------- VQ prep: codebook -> fp16 + ||c||^2 (vectorized) ----------------
__global__ __launch_bounds__(256, 2) void vq_prep(
    const float* __restrict__ cb, _Float16* __restrict__ cbh, float* __restrict__ cnorm)
{
    const int t = threadIdx.x;
    const int wave = t >> 6, lane = t & 63;
    const int e   = blockIdx.x*16 + wave*4 + (lane >> 4);
    const int sub = lane & 15;
    const float4 v = *(const float4*)(cb + (size_t)e*64 + sub*4);
    f16x2 h0 = pkrtz(v.x, v.y);
    f16x2 h1 = pkrtz(v.z, v.w);
    f16x4 hv; hv[0]=h0[0]; hv[1]=h0[1]; hv[2]=h1[0]; hv[3]=h1[1];
    *(f16x4*)(cbh + (size_t)e*64 + sub*4) = hv;
    float d = v.x*v.x + v.y*v.y + v.z*v.z + v.w*v.w;
    #pragma unroll
    for (int s=1; s<16; s<<=1) d += __shfl_xor(d, s, 64);
    if (sub == 0) cnorm[e] = d;
}

// ---------------- VQ GEMM: argmin_k (||c||^2 - 2 z.c) via fp16 MFMA ----------------
__global__ __launch_bounds__(256, 2) void vq_mfma(
    const _Float16* __restrict__ zh, const _Float16* __restrict__ cbh,
    const float* __restrict__ cnorm,
    float* __restrict__ pval, int* __restrict__ pidx)
{
    const int t    = threadIdx.x;
    const int wave = t >> 6;
    const int lane = t & 63;
    const int col  = lane & 15;
    const int quad = lane >> 4;
    const int rb   = blockIdx.x >> 5;
    const int ns   = blockIdx.x & 31;
    const int rowbase = rb*64 + wave*16;

    f16x8 az[2];
    az[0] = *(const f16x8*)&zh[(size_t)(rowbase+col)*64 + quad*8];
    az[1] = *(const f16x8*)&zh[(size_t)(rowbase+col)*64 + quad*8 + 32];

    float best[4] = {__builtin_inff(),__builtin_inff(),__builtin_inff(),__builtin_inff()};
    int   bidx[4] = {0,0,0,0};

    int e = ns*256;
    f16x8 bf0 = *(const f16x8*)&cbh[(size_t)(e+col)*64 + quad*8];
    f16x8 bf1 = *(const f16x8*)&cbh[(size_t)(e+col)*64 + quad*8 + 32];
    float cn  = cnorm[e+col];

    #pragma unroll 1
    for (int nt=0; nt<16; nt++){
        f16x8 c0 = bf0, c1 = bf1;
        float cnc = cn;
        int ec = e;
        if (nt < 15){
            e += 16;
            bf0 = *(const f16x8*)&cbh[(size_t)(e+col)*64 + quad*8];
            bf1 = *(const f16x8*)&cbh[(size_t)(e+col)*64 + quad*8 + 32];
            cn  = cnorm[e+col];
        }
        f32x4 acc; acc[0]=0.f; acc[1]=0.f; acc[2]=0.f; acc[3]=0.f;
        acc = __builtin_amdgcn_mfma_f32_16x16x32_f16(az[0], c0, acc, 0,0,0);
        acc = __builtin_amdgcn_mfma_f32_16x16x32_f16(az[1], c1, acc, 0,0,0);
        int myidx = ec + col;
        #pragma unroll
        for (int r=0; r<4; r++){
            float d = fmaf(-2.0f, acc[r], cnc);
            if (d < best[r]){ best[r] = d; bidx[r] = myidx; }
        }
    }

    #pragma unroll
    for (int r=0; r<4; r++){
        float v = best[r]; int i = bidx[r];
        #pragma unroll
        for (int s=1; s<16; s<<=1){
            float ov = __shfl_xor(v, s, 64);
            int   oi = __shfl_xor(i, s, 64);
            if (ov < v || (ov == v && oi < i)){ v = ov; i = oi; }
        }
        if (col == 0){
            int row = rowbase + quad*4 + r;
            pval[row*32 + ns] = v;
            pidx[row*32 + ns] = i;
        }
    }
}

// ---------------- decoder (argmin-merge + 64->128->64->3) + per-b loss partial ----------------
__global__ __launch_bounds__(128, 2) void decoder_kernel(
    const float* __restrict__ z,
    const float* __restrict__ pval, const int* __restrict__ pidx,
    const float* __restrict__ cb,
    const float* __restrict__ U1, const float* __restrict__ c1,
    const float* __restrict__ U2, const float* __restrict__ c2,
    const float* __restrict__ U3, const float* __restrict__ c3,
    float* __restrict__ xrec, float* __restrict__ loss_part)
{
    const int b = blockIdx.x;
    const int t = threadIdx.x;
    __shared__ int kk_s;
    __shared__ float zst[64];
    __shared__ float g1[128];
    __shared__ float g2[64];
    if (t < 32){
        float v = pval[b*32 + t]; int i = pidx[b*32 + t];
        #pragma unroll
        for (int s=1; s<32; s<<=1){
            float ov = __shfl_xor(v, s, 32);
            int   oi = __shfl_xor(i, s, 32);
            if (ov < v || (ov == v && oi < i)){ v = ov; i = oi; }
        }
        if (t==0) kk_s = i;
    }
    __syncthreads();
    const int kk = kk_s;
    if (t < 64){
        float zv = z[(size_t)b*64 + t];
        float zq = cb[(size_t)kk*64 + t];
        float diff = zq - zv;
        zst[t] = zv + diff;
        float p = diff*diff;
        #pragma unroll
        for (int s=32;s>0;s>>=1) p += __shfl_xor(p, s, 64);
        if (t==0) loss_part[b] = p;
    }
    __syncthreads();
    {
        float v = c1[t];
        #pragma unroll
        for (int d=0; d<64; d++) v = fmaf(zst[d], U1[d*128+t], v);
        g1[t] = leakyf(v);
    }
    __syncthreads();
    if (t < 64){
        float v = c2[t];
        #pragma unroll
        for (int j=0;j<128;j++) v = fmaf(g1[j], U2[j*64+t], v);
        g2[t] = leakyf(v);
    }
    __syncthreads();
    if (t < 3){
        float v = c3[t];
        #pragma unroll
        for (int j=0;j<64;j++) v = fmaf(g2[j], U3[j*3+t], v);
        xrec[(size_t)b*3 + t] = v;
    }
}

__global__ __launch_bounds__(256, 1) void loss_kernel(
    const float* __restrict__ loss_part, float* __restrict__ out)
{
    const int t = threadIdx.x;
    float s = 0.f;
    for (int i=t;i<BB;i+=256) s += loss_part[i];
    #pragma unroll
    for (int sh=32;sh>0;sh>>=1) s += __shfl_xor(s, sh, 64);
    __shared__ float w[4];
    if ((t&63)==0) w[t>>6] = s;
    __syncthreads();
    if (t==0) out[0] = (w[0]+w[1]+w[2]+w[3]) * (1.25f / 65536.0f);
}

extern "C" void kernel_launch(void* const* d_in, const int* in_sizes, int n_in,
                              void* d_out, int out_size, void* d_ws, size_t ws_size,
                              hipStream_t stream)
{
    const float* x  = (const float*)d_in[0];
    const float* W1 = (const float*)d_in[1];
    const float* b1 = (const float*)d_in[2];
    const float* W2 = (const float*)d_in[3];
    const float* b2 = (const float*)d_in[4];
    const float* W3 = (const float*)d_in[5];
    const float* b3 = (const float*)d_in[6];
    const float* cb = (const float*)d_in[7];
    const float* U1 = (const float*)d_in[8];
    const float* c1 = (const float*)d_in[9];
    const float* U2 = (const float*)d_in[10];
    const float* c2 = (const float*)d_in[11];
    const float* U3 = (const float*)d_in[12];
    const float* c3 = (const float*)d_in[13];

    float* out  = (float*)d_out;
    float* xrec = out;              // [1024*3]
    float* loss = out + 3072;       // [1]
    float* z    = out + 3073;       // [1024*64]

    char* ws = (char*)d_ws;
    float*    lp    = (float*)ws;                       // 4 KB
    _Float16* zh    = (_Float16*)(ws + 4096);           // 128 KB
    float*    cnorm = (float*)(ws + 135168);            // 32 KB
    float*    pval  = (float*)(ws + 167936);            // 128 KB
    int*      pidx  = (int*)(ws + 299008);              // 128 KB
    _Float16* cbh   = (_Float16*)(ws + 430080);         // 1 MB

    hipLaunchKernelGGL(vq_prep, dim3(512), dim3(256), 0, stream, cb, cbh, cnorm);
    hipLaunchKernelGGL(encoder_mfma, dim3(BB), dim3(256), 0, stream,
                       x, W1, b1, W2, b2, W3, b3, z, zh);
    hipLaunchKernelGGL(vq_mfma, dim3(512), dim3(256), 0, stream, zh, cbh, cnorm, pval, pidx);
    hipLaunchKernelGGL(decoder_kernel, dim3(BB), dim3(128), 0, stream,
                       z, pval, pidx, cb, U1, c1, U2, c2, U3, c3, xrec, lp);
    hipLaunchKernelGGL(loss_kernel, dim3(1), dim3(256), 0, stream, lp, loss);
}

// Round 6
// 211.386 us; speedup vs baseline: 17.3597x; 1.0699x over previous
//
#include <hip/hip_runtime.h>
#include <hip/hip_bf16.h>

#define BB 1024
#define LL 2048
#define KK 8192

typedef _Float16 f16x8 __attribute__((ext_vector_type(8)));
typedef _Float16 f16x4 __attribute__((ext_vector_type(4)));
typedef _Float16 f16x2 __attribute__((ext_vector_type(2)));
typedef float    f32x4 __attribute__((ext_vector_type(4)));

__device__ __forceinline__ float leakyf(float v){ return fmaxf(v, 0.001f*v); }
__device__ __forceinline__ f16x2 pkrtz(float a, float b){
    return __builtin_bit_cast(f16x2, __builtin_amdgcn_cvt_pkrtz(a, b));
}
// MFMA with the B operand (weights) pinned to AGPRs — frees arch VGPRs (no spills).
__device__ __forceinline__ f32x4 mfma_w(f16x8 a, f16x8 w_agpr, f32x4 c){
    f32x4 d;
    asm("v_mfma_f32_16x16x32_f16 %0, %1, %2, %3"
        : "=v"(d) : "v"(a), "a"(w_agpr), "v"(c));
    return d;
}

// ---------------- encoder: fused conv1x1 (3->64->128->64) + global max over L ----------------
// One block per b, 4 waves; wave = 16 positions/iter, 32 iters. W2/W3 live in AGPRs
// (inline-asm MFMA, "a" constraint); arch VGPRs hold only dynamic state -> no scratch.
__global__ __launch_bounds__(256, 2) void encoder_mfma(
    const float* __restrict__ x,
    const float* __restrict__ W1, const float* __restrict__ b1,
    const float* __restrict__ W2, const float* __restrict__ b2,
    const float* __restrict__ W3, const float* __restrict__ b3,
    float* __restrict__ z_out, _Float16* __restrict__ zh_out)
{
    const int b    = blockIdx.x;
    const int t    = threadIdx.x;
    const int wave = t >> 6;
    const int lane = t & 63;
    const int col  = lane & 15;
    const int quad = lane >> 4;

    __shared__ __align__(16) _Float16 h2lds[4*16*136];  // 272B row stride, quad-XOR swizzled cols
    __shared__ float red[4][64];

    // B-frags layer 2 (AGPR-resident): B[k=c][n=o2], o2 = nt*16+col, c = quad*8+32ks+j
    f16x8 w2f[2][8];
    #pragma unroll
    for (int ks=0; ks<2; ks++){
        #pragma unroll
        for (int nt=0; nt<8; nt++){
            const float* p = W2 + (nt*16+col)*64 + quad*8 + 32*ks;
            f16x8 f;
            #pragma unroll
            for (int j=0;j<8;j++) f[j] = (_Float16)p[j];
            w2f[ks][nt] = f;
        }
    }
    // B-frags layer 3 (AGPR-resident): B[k=o2][n=o3]
    f16x8 w3f[4][4];
    #pragma unroll
    for (int ks=0; ks<4; ks++){
        #pragma unroll
        for (int nt=0; nt<4; nt++){
            const float* p = W3 + (nt*16+col)*128 + quad*8 + 32*ks;
            f16x8 f;
            #pragma unroll
            for (int j=0;j<8;j++) f[j] = (_Float16)p[j];
            w3f[ks][nt] = f;
        }
    }
    // layer-1 weights packed per-lane (channels quad*8 + 2*j2{+1} + 32ks)
    f16x2 w1p[2][4][3];
    f16x2 b1p[2][4];
    #pragma unroll
    for (int ks=0; ks<2; ks++){
        #pragma unroll
        for (int j2=0; j2<4; j2++){
            int c0 = quad*8 + 2*j2 + 32*ks;
            #pragma unroll
            for (int i=0;i<3;i++){
                f16x2 w; w[0] = (_Float16)W1[c0*3+i]; w[1] = (_Float16)W1[(c0+1)*3+i];
                w1p[ks][j2][i] = w;
            }
            f16x2 bb; bb[0] = (_Float16)b1[c0]; bb[1] = (_Float16)b1[c0+1];
            b1p[ks][j2] = bb;
        }
    }
    // b2 as packed pairs (same channel both halves; pair = two position-rows)
    f16x2 b2p[8];
    #pragma unroll
    for (int nt=0; nt<8; nt++){
        _Float16 bv = (_Float16)b2[nt*16+col];
        f16x2 p; p[0]=bv; p[1]=bv; b2p[nt]=p;
    }

    f16x2 k001; k001[0] = (_Float16)0.001f; k001[1] = (_Float16)0.001f;
    f32x4 zc; zc[0]=0.f; zc[1]=0.f; zc[2]=0.f; zc[3]=0.f;

    f32x4 hm[4];
    #pragma unroll
    for (int nt=0;nt<4;nt++){
        hm[nt][0] = -__builtin_inff(); hm[nt][1] = -__builtin_inff();
        hm[nt][2] = -__builtin_inff(); hm[nt][3] = -__builtin_inff();
    }

    const float* xb = x + (size_t)b*3*LL;
    const int wave_off = wave*2176;          // 16*136
    const int pbase = wave*16 + col;
    const int rswz  = (col >> 2) << 4;       // read-side row-quad XOR

    float x0n = xb[pbase], x1n = xb[LL+pbase], x2n = xb[2*LL+pbase];

    #pragma unroll 1
    for (int it=0; it<LL/64; it++){
        const float x0 = x0n, x1 = x1n, x2 = x2n;
        {   // prefetch next iter's x
            int itn = it+1 < 32 ? it+1 : 31;
            int pn = itn*64 + pbase;
            x0n = xb[pn]; x1n = xb[LL+pn]; x2n = xb[2*LL+pn];
        }
        f16x2 xh0; xh0[0] = (_Float16)x0; xh0[1] = xh0[0];
        f16x2 xh1; xh1[0] = (_Float16)x1; xh1[1] = xh1[0];
        f16x2 xh2; xh2[0] = (_Float16)x2; xh2[1] = xh2[0];

        // layer 1 -> A-frags (packed leaky)
        f16x8 a2[2];
        #pragma unroll
        for (int ks=0; ks<2; ks++){
            f16x8 a;
            #pragma unroll
            for (int j2=0; j2<4; j2++){
                f16x2 v = b1p[ks][j2];
                v += w1p[ks][j2][0]*xh0;
                v += w1p[ks][j2][1]*xh1;
                v += w1p[ks][j2][2]*xh2;
                v = __builtin_elementwise_max(v, v*k001);
                a[2*j2]   = v[0];
                a[2*j2+1] = v[1];
            }
            a2[ks] = a;
        }

        // layer 2: AGPR-weight MFMAs, packed epilogue, swizzled b16 stores
        #pragma unroll
        for (int nt=0; nt<8; nt++){
            f32x4 acc = mfma_w(a2[0], w2f[0][nt], zc);
            acc = mfma_w(a2[1], w2f[1][nt], acc);
            f16x2 p01 = pkrtz(acc[0], acc[1]);
            f16x2 p23 = pkrtz(acc[2], acc[3]);
            p01 += b2p[nt];  p23 += b2p[nt];
            p01 = __builtin_elementwise_max(p01, p01*k001);
            p23 = __builtin_elementwise_max(p23, p23*k001);
            _Float16* wp = &h2lds[wave_off + quad*4*136 + ((nt ^ quad)<<4) + col];
            wp[0]     = p01[0];
            wp[136]   = p01[1];
            wp[272]   = p23[0];
            wp[408]   = p23[1];
        }

        // layer 3: swizzled b128 reads, AGPR-weight MFMAs
        f16x8 a30 = *(const f16x8*)&h2lds[wave_off + col*136 + (( 0 + quad*8) ^ rswz)];
        f16x8 a31 = *(const f16x8*)&h2lds[wave_off + col*136 + ((32 + quad*8) ^ rswz)];
        f16x8 a32 = *(const f16x8*)&h2lds[wave_off + col*136 + ((64 + quad*8) ^ rswz)];
        f16x8 a33 = *(const f16x8*)&h2lds[wave_off + col*136 + ((96 + quad*8) ^ rswz)];
        #pragma unroll
        for (int nt=0; nt<4; nt++){
            f32x4 acc = mfma_w(a30, w3f[0][nt], zc);
            acc = mfma_w(a31, w3f[1][nt], acc);
            acc = mfma_w(a32, w3f[2][nt], acc);
            acc = mfma_w(a33, w3f[3][nt], acc);
            hm[nt][0] = fmaxf(hm[nt][0], acc[0]);
            hm[nt][1] = fmaxf(hm[nt][1], acc[1]);
            hm[nt][2] = fmaxf(hm[nt][2], acc[2]);
            hm[nt][3] = fmaxf(hm[nt][3], acc[3]);
        }
    }

    #pragma unroll
    for (int nt=0; nt<4; nt++){
        float v = fmaxf(fmaxf(hm[nt][0], hm[nt][1]), fmaxf(hm[nt][2], hm[nt][3]));
        v = fmaxf(v, __shfl_xor(v, 16, 64));
        v = fmaxf(v, __shfl_xor(v, 32, 64));
        if (quad == 0) red[wave][nt*16 + col] = v;
    }
    __syncthreads();
    if (t < 64){
        float v = fmaxf(fmaxf(red[0][t], red[1][t]), fmaxf(red[2][t], red[3][t])) + b3[t];
        z_out[(size_t)b*64 + t] = v;
        zh_out[(size_t)b*64 + t] = (_Float16)v;
    }
}

// ---------------- VQ: fused codebook-slice prep (LDS) + argmin GEMM ----------------
// grid 512: rb = bid>>5 (16 row-blocks of 64 rows), ns = bid&31 (32 slices of 256 entries).
__global__ __launch_bounds__(256, 2) void vq_mfma(
    const _Float16* __restrict__ zh, const float* __restrict__ cb,
    float* __restrict__ pval, int* __restrict__ pidx)
{
    const int t    = threadIdx.x;
    const int wave = t >> 6;
    const int lane = t & 63;
    const int col  = lane & 15;
    const int quad = lane >> 4;
    const int rb   = blockIdx.x >> 5;
    const int ns   = blockIdx.x & 31;

    __shared__ __align__(16) _Float16 cbl[256*72];   // 72-half stride: conflict-free b128 reads
    __shared__ float cnl[256];

    // stage this block's 256-entry slice: fp32 -> fp16 LDS + ||c||^2
    const int eoff = wave*4 + (lane >> 4);
    const int sub  = lane & 15;
    #pragma unroll 4
    for (int p=0; p<16; p++){
        const int el = p*16 + eoff;
        const float4 v = *(const float4*)(cb + ((size_t)(ns*256 + el))*64 + sub*4);
        f16x2 h0 = pkrtz(v.x, v.y);
        f16x2 h1 = pkrtz(v.z, v.w);
        f16x4 hv; hv[0]=h0[0]; hv[1]=h0[1]; hv[2]=h1[0]; hv[3]=h1[1];
        *(f16x4*)(cbl + el*72 + sub*4) = hv;
        float d = v.x*v.x + v.y*v.y + v.z*v.z + v.w*v.w;
        #pragma unroll
        for (int s=1; s<16; s<<=1) d += __shfl_xor(d, s, 64);
        if (sub == 0) cnl[el] = d;
    }
    __syncthreads();

    const int rowbase = rb*64 + wave*16;
    f16x8 az[2];
    az[0] = *(const f16x8*)&zh[(size_t)(rowbase+col)*64 + quad*8];
    az[1] = *(const f16x8*)&zh[(size_t)(rowbase+col)*64 + quad*8 + 32];

    f32x4 zc; zc[0]=0.f; zc[1]=0.f; zc[2]=0.f; zc[3]=0.f;
    float best[4] = {__builtin_inff(),__builtin_inff(),__builtin_inff(),__builtin_inff()};
    int   bidx[4] = {0,0,0,0};

    #pragma unroll 4
    for (int nt=0; nt<16; nt++){
        const int el = nt*16 + col;
        f16x8 c0 = *(const f16x8*)&cbl[el*72 + quad*8];
        f16x8 c1 = *(const f16x8*)&cbl[el*72 + quad*8 + 32];
        float cnc = cnl[el];
        f32x4 acc = __builtin_amdgcn_mfma_f32_16x16x32_f16(az[0], c0, zc, 0,0,0);
        acc = __builtin_amdgcn_mfma_f32_16x16x32_f16(az[1], c1, acc, 0,0,0);
        const int myidx = ns*256 + el;
        #pragma unroll
        for (int r=0; r<4; r++){
            float d = fmaf(-2.0f, acc[r], cnc);
            if (d < best[r]){ best[r] = d; bidx[r] = myidx; }
        }
    }

    #pragma unroll
    for (int r=0; r<4; r++){
        float v = best[r]; int i = bidx[r];
        #pragma unroll
        for (int s=1; s<16; s<<=1){
            float ov = __shfl_xor(v, s, 64);
            int   oi = __shfl_xor(i, s, 64);
            if (ov < v || (ov == v && oi < i)){ v = ov; i = oi; }
        }
        if (col == 0){
            int row = rowbase + quad*4 + r;
            pval[row*32 + ns] = v;
            pidx[row*32 + ns] = i;
        }
    }
}

// ---------------- decoder (argmin-merge + 64->128->64->3) + per-b loss partial ----------------
__global__ __launch_bounds__(128, 2) void decoder_kernel(
    const float* __restrict__ z,
    const float* __restrict__ pval, const int* __restrict__ pidx,
    const float* __restrict__ cb,
    const float* __restrict__ U1, const float* __restrict__ c1,
    const float* __restrict__ U2, const float* __restrict__ c2,
    const float* __restrict__ U3, const float* __restrict__ c3,
    float* __restrict__ xrec, float* __restrict__ loss_part)
{
    const int b = blockIdx.x;
    const int t = threadIdx.x;
    __shared__ int kk_s;
    __shared__ float zst[64];
    __shared__ float g1[128];
    __shared__ float g2[64];
    if (t < 32){
        float v = pval[b*32 + t]; int i = pidx[b*32 + t];
        #pragma unroll
        for (int s=1; s<32; s<<=1){
            float ov = __shfl_xor(v, s, 32);
            int   oi = __shfl_xor(i, s, 32);
            if (ov < v || (ov == v && oi < i)){ v = ov; i = oi; }
        }
        if (t==0) kk_s = i;
    }
    __syncthreads();
    const int kk = kk_s;
    if (t < 64){
        float zv = z[(size_t)b*64 + t];
        float zq = cb[(size_t)kk*64 + t];
        float diff = zq - zv;
        zst[t] = zv + diff;
        float p = diff*diff;
        #pragma unroll
        for (int s=32;s>0;s>>=1) p += __shfl_xor(p, s, 64);
        if (t==0) loss_part[b] = p;
    }
    __syncthreads();
    {
        float v = c1[t];
        #pragma unroll
        for (int d=0; d<64; d++) v = fmaf(zst[d], U1[d*128+t], v);
        g1[t] = leakyf(v);
    }
    __syncthreads();
    if (t < 64){
        float v = c2[t];
        #pragma unroll
        for (int j=0;j<128;j++) v = fmaf(g1[j], U2[j*64+t], v);
        g2[t] = leakyf(v);
    }
    __syncthreads();
    if (t < 3){
        float v = c3[t];
        #pragma unroll
        for (int j=0;j<64;j++) v = fmaf(g2[j], U3[j*3+t], v);
        xrec[(size_t)b*3 + t] = v;
    }
}

__global__ __launch_bounds__(256, 1) void loss_kernel(
    const float* __restrict__ loss_part, float* __restrict__ out)
{
    const int t = threadIdx.x;
    float s = 0.f;
    for (int i=t;i<BB;i+=256) s += loss_part[i];
    #pragma unroll
    for (int sh=32;sh>0;sh>>=1) s += __shfl_xor(s, sh, 64);
    __shared__ float w[4];
    if ((t&63)==0) w[t>>6] = s;
    __syncthreads();
    if (t==0) out[0] = (w[0]+w[1]+w[2]+w[3]) * (1.25f / 65536.0f);
}

extern "C" void kernel_launch(void* const* d_in, const int* in_sizes, int n_in,
                              void* d_out, int out_size, void* d_ws, size_t ws_size,
                              hipStream_t stream)
{
    const float* x  = (const float*)d_in[0];
    const float* W1 = (const float*)d_in[1];
    const float* b1 = (const float*)d_in[2];
    const float* W2 = (const float*)d_in[3];
    const float* b2 = (const float*)d_in[4];
    const float* W3 = (const float*)d_in[5];
    const float* b3 = (const float*)d_in[6];
    const float* cb = (const float*)d_in[7];
    const float* U1 = (const float*)d_in[8];
    const float* c1 = (const float*)d_in[9];
    const float* U2 = (const float*)d_in[10];
    const float* c2 = (const float*)d_in[11];
    const float* U3 = (const float*)d_in[12];
    const float* c3 = (const float*)d_in[13];

    float* out  = (float*)d_out;
    float* xrec = out;              // [1024*3]
    float* loss = out + 3072;       // [1]
    float* z    = out + 3073;       // [1024*64]

    char* ws = (char*)d_ws;
    float*    lp    = (float*)ws;                       // 4 KB
    _Float16* zh    = (_Float16*)(ws + 4096);           // 128 KB
    float*    pval  = (float*)(ws + 135168);            // 128 KB
    int*      pidx  = (int*)(ws + 266240);              // 128 KB

    hipLaunchKernelGGL(encoder_mfma, dim3(BB), dim3(256), 0, stream,
                       x, W1, b1, W2, b2, W3, b3, z, zh);
    hipLaunchKernelGGL(vq_mfma, dim3(512), dim3(256), 0, stream, zh, cb, pval, pidx);
    hipLaunchKernelGGL(decoder_kernel, dim3(BB), dim3(128), 0, stream,
                       z, pval, pidx, cb, U1, c1, U2, c2, U3, c3, xrec, lp);
    hipLaunchKernelGGL(loss_kernel, dim3(1), dim3(256), 0, stream, lp, loss);
}

// Round 7
// 206.415 us; speedup vs baseline: 17.7778x; 1.0241x over previous
//
#include <hip/hip_runtime.h>
#include <hip/hip_bf16.h>

#define BB 1024
#define LL 2048
#define KK 8192

typedef _Float16 f16x8 __attribute__((ext_vector_type(8)));
typedef _Float16 f16x4 __attribute__((ext_vector_type(4)));
typedef _Float16 f16x2 __attribute__((ext_vector_type(2)));
typedef float    f32x4 __attribute__((ext_vector_type(4)));

__device__ __forceinline__ float leakyf(float v){ return fmaxf(v, 0.001f*v); }
__device__ __forceinline__ f16x2 pkrtz(float a, float b){
    return __builtin_bit_cast(f16x2, __builtin_amdgcn_cvt_pkrtz(a, b));
}
// MFMA with the B operand (weights) pinned to AGPRs — frees arch VGPRs (no spills).
__device__ __forceinline__ f32x4 mfma_w(f16x8 a, f16x8 w_agpr, f32x4 c){
    f32x4 d;
    asm("v_mfma_f32_16x16x32_f16 %0, %1, %2, %3"
        : "=v"(d) : "v"(a), "a"(w_agpr), "v"(c));
    return d;
}

// ---------------- encoder: fused conv1x1 (3->64->128->64) + global max over L ----------------
// One block per b, 4 waves; wave = 16 positions/iter, 32 iters. W2/W3 live in AGPRs.
// h2 C->A transform: DPP+perm pack to dwords (VALU pipe), ds_write2_b32 stores (2 LDS
// insts/nt -> 8/iter vs 32 b16), quad-XOR bank swizzle, b128 reads.
__global__ __launch_bounds__(256, 2) void encoder_mfma(
    const float* __restrict__ x,
    const float* __restrict__ W1, const float* __restrict__ b1,
    const float* __restrict__ W2, const float* __restrict__ b2,
    const float* __restrict__ W3, const float* __restrict__ b3,
    float* __restrict__ z_out, _Float16* __restrict__ zh_out)
{
    const int b    = blockIdx.x;
    const int t    = threadIdx.x;
    const int wave = t >> 6;
    const int lane = t & 63;
    const int col  = lane & 15;
    const int quad = lane >> 4;

    __shared__ __align__(16) unsigned h2l[4*16*68];  // dword view; row stride 68 dw (=136 halves)
    __shared__ float red[4][64];
    _Float16* h2h = (_Float16*)h2l;

    // B-frags layer 2 (AGPR-resident): B[k=c][n=o2], o2 = nt*16+col, c = quad*8+32ks+j
    f16x8 w2f[2][8];
    #pragma unroll
    for (int ks=0; ks<2; ks++){
        #pragma unroll
        for (int nt=0; nt<8; nt++){
            const float* p = W2 + (nt*16+col)*64 + quad*8 + 32*ks;
            f16x8 f;
            #pragma unroll
            for (int j=0;j<8;j++) f[j] = (_Float16)p[j];
            w2f[ks][nt] = f;
        }
    }
    // B-frags layer 3 (AGPR-resident): B[k=o2][n=o3]
    f16x8 w3f[4][4];
    #pragma unroll
    for (int ks=0; ks<4; ks++){
        #pragma unroll
        for (int nt=0; nt<4; nt++){
            const float* p = W3 + (nt*16+col)*128 + quad*8 + 32*ks;
            f16x8 f;
            #pragma unroll
            for (int j=0;j<8;j++) f[j] = (_Float16)p[j];
            w3f[ks][nt] = f;
        }
    }
    // layer-1 weights packed per-lane (channels quad*8 + 2*j2{+1} + 32ks)
    f16x2 w1p[2][4][3];
    f16x2 b1p[2][4];
    #pragma unroll
    for (int ks=0; ks<2; ks++){
        #pragma unroll
        for (int j2=0; j2<4; j2++){
            int c0 = quad*8 + 2*j2 + 32*ks;
            #pragma unroll
            for (int i=0;i<3;i++){
                f16x2 w; w[0] = (_Float16)W1[c0*3+i]; w[1] = (_Float16)W1[(c0+1)*3+i];
                w1p[ks][j2][i] = w;
            }
            f16x2 bb; bb[0] = (_Float16)b1[c0]; bb[1] = (_Float16)b1[c0+1];
            b1p[ks][j2] = bb;
        }
    }
    // b2 as packed pairs (same channel both halves; pair = two position-rows)
    f16x2 b2p[8];
    #pragma unroll
    for (int nt=0; nt<8; nt++){
        _Float16 bv = (_Float16)b2[nt*16+col];
        f16x2 p; p[0]=bv; p[1]=bv; b2p[nt]=p;
    }

    f16x2 k001; k001[0] = (_Float16)0.001f; k001[1] = (_Float16)0.001f;
    f32x4 zc; zc[0]=0.f; zc[1]=0.f; zc[2]=0.f; zc[3]=0.f;

    f32x4 hm[4];
    #pragma unroll
    for (int nt=0;nt<4;nt++){
        hm[nt][0] = -__builtin_inff(); hm[nt][1] = -__builtin_inff();
        hm[nt][2] = -__builtin_inff(); hm[nt][3] = -__builtin_inff();
    }

    const float* xb = x + (size_t)b*3*LL;
    const int pbase = wave*16 + col;
    const int rswz  = (col >> 2) << 4;       // read-side row-quad XOR (halves domain)
    // write base (dwords): row = quad*4 + (col&1); dword col = col>>1 (+ (nt^quad)*8 in loop)
    const int wbase = wave*1088 + (quad*4 + (col&1))*68 + (col>>1);
    // perm selector: even lane -> {P.lo, Q.lo} (pos r), odd -> {Q.hi, P.hi} (pos r+1)
    const unsigned selA = (col & 1) ? 0x03020706u : 0x05040100u;

    float x0n = xb[pbase], x1n = xb[LL+pbase], x2n = xb[2*LL+pbase];

    #pragma unroll 1
    for (int it=0; it<LL/64; it++){
        const float x0 = x0n, x1 = x1n, x2 = x2n;
        {   // prefetch next iter's x
            int itn = it+1 < 32 ? it+1 : 31;
            int pn = itn*64 + pbase;
            x0n = xb[pn]; x1n = xb[LL+pn]; x2n = xb[2*LL+pn];
        }
        f16x2 xh0; xh0[0] = (_Float16)x0; xh0[1] = xh0[0];
        f16x2 xh1; xh1[0] = (_Float16)x1; xh1[1] = xh1[0];
        f16x2 xh2; xh2[0] = (_Float16)x2; xh2[1] = xh2[0];

        // layer 1 -> A-frags (packed leaky)
        f16x8 a2[2];
        #pragma unroll
        for (int ks=0; ks<2; ks++){
            f16x8 a;
            #pragma unroll
            for (int j2=0; j2<4; j2++){
                f16x2 v = b1p[ks][j2];
                v += w1p[ks][j2][0]*xh0;
                v += w1p[ks][j2][1]*xh1;
                v += w1p[ks][j2][2]*xh2;
                v = __builtin_elementwise_max(v, v*k001);
                a[2*j2]   = v[0];
                a[2*j2+1] = v[1];
            }
            a2[ks] = a;
        }

        // layer 2: AGPR-weight MFMAs; epilogue packs (2pos x 1ch) -> (1pos x 2ch) dwords
        // via DPP xor-1 + v_perm, then one ds_write2_b32 per nt.
        #pragma unroll
        for (int nt=0; nt<8; nt++){
            f32x4 acc = mfma_w(a2[0], w2f[0][nt], zc);
            acc = mfma_w(a2[1], w2f[1][nt], acc);
            f16x2 p01 = pkrtz(acc[0], acc[1]);   // pos r, r+1  (r = quad*4)
            f16x2 p23 = pkrtz(acc[2], acc[3]);   // pos r+2, r+3
            p01 += b2p[nt];  p23 += b2p[nt];
            p01 = __builtin_elementwise_max(p01, p01*k001);
            p23 = __builtin_elementwise_max(p23, p23*k001);
            unsigned P01 = __builtin_bit_cast(unsigned, p01);
            unsigned P23 = __builtin_bit_cast(unsigned, p23);
            unsigned Q01 = (unsigned)__builtin_amdgcn_mov_dpp((int)P01, 0xB1, 0xF, 0xF, true);
            unsigned Q23 = (unsigned)__builtin_amdgcn_mov_dpp((int)P23, 0xB1, 0xF, 0xF, true);
            unsigned d0 = __builtin_amdgcn_perm(Q01, P01, selA);
            unsigned d1 = __builtin_amdgcn_perm(Q23, P23, selA);
            unsigned* wp = &h2l[wbase + ((nt ^ quad)<<3)];
            wp[0]   = d0;     // pos r(+0/1), ch pair
            wp[136] = d1;     // pos r+2(+0/1)  -> ds_write2_b32
        }

        // layer 3: swizzled b128 reads, AGPR-weight MFMAs
        const int roff = wave*2176 + col*136;
        f16x8 a30 = *(const f16x8*)&h2h[roff + (( 0 + quad*8) ^ rswz)];
        f16x8 a31 = *(const f16x8*)&h2h[roff + ((32 + quad*8) ^ rswz)];
        f16x8 a32 = *(const f16x8*)&h2h[roff + ((64 + quad*8) ^ rswz)];
        f16x8 a33 = *(const f16x8*)&h2h[roff + ((96 + quad*8) ^ rswz)];
        #pragma unroll
        for (int nt=0; nt<4; nt++){
            f32x4 acc = mfma_w(a30, w3f[0][nt], zc);
            acc = mfma_w(a31, w3f[1][nt], acc);
            acc = mfma_w(a32, w3f[2][nt], acc);
            acc = mfma_w(a33, w3f[3][nt], acc);
            hm[nt][0] = fmaxf(hm[nt][0], acc[0]);
            hm[nt][1] = fmaxf(hm[nt][1], acc[1]);
            hm[nt][2] = fmaxf(hm[nt][2], acc[2]);
            hm[nt][3] = fmaxf(hm[nt][3], acc[3]);
        }
    }

    #pragma unroll
    for (int nt=0; nt<4; nt++){
        float v = fmaxf(fmaxf(hm[nt][0], hm[nt][1]), fmaxf(hm[nt][2], hm[nt][3]));
        v = fmaxf(v, __shfl_xor(v, 16, 64));
        v = fmaxf(v, __shfl_xor(v, 32, 64));
        if (quad == 0) red[wave][nt*16 + col] = v;
    }
    __syncthreads();
    if (t < 64){
        float v = fmaxf(fmaxf(red[0][t], red[1][t]), fmaxf(red[2][t], red[3][t])) + b3[t];
        z_out[(size_t)b*64 + t] = v;
        zh_out[(size_t)b*64 + t] = (_Float16)v;
    }
}

// ---------------- cnorm: ||c||^2 per codebook entry ----------------
__global__ __launch_bounds__(256, 4) void cnorm_kernel(
    const float* __restrict__ cb, float* __restrict__ cnorm)
{
    const int e = blockIdx.x*256 + threadIdx.x;
    const float4* p = (const float4*)(cb + (size_t)e*64);
    float s = 0.f;
    #pragma unroll
    for (int q=0;q<16;q++){
        float4 v = p[q];
        s += v.x*v.x + v.y*v.y + v.z*v.z + v.w*v.w;
    }
    cnorm[e] = s;
}

// ---------------- VQ: fused codebook-slice fp16 staging + argmin GEMM ----------------
// grid 512: rb = bid>>5 (16 row-blocks of 64 rows), ns = bid&31 (32 slices of 256 entries).
__global__ __launch_bounds__(256, 2) void vq_mfma(
    const _Float16* __restrict__ zh, const float* __restrict__ cb,
    const float* __restrict__ cnorm,
    float* __restrict__ pval, int* __restrict__ pidx)
{
    const int t    = threadIdx.x;
    const int wave = t >> 6;
    const int lane = t & 63;
    const int col  = lane & 15;
    const int quad = lane >> 4;
    const int rb   = blockIdx.x >> 5;
    const int ns   = blockIdx.x & 31;

    __shared__ __align__(16) _Float16 cbl[256*72];   // 72-half stride: conflict-free b128 reads

    // stage this block's 256-entry slice: fp32 -> fp16 LDS
    const int eoff = wave*4 + (lane >> 4);
    const int sub  = lane & 15;
    #pragma unroll 4
    for (int p=0; p<16; p++){
        const int el = p*16 + eoff;
        const float4 v = *(const float4*)(cb + ((size_t)(ns*256 + el))*64 + sub*4);
        f16x2 h0 = pkrtz(v.x, v.y);
        f16x2 h1 = pkrtz(v.z, v.w);
        f16x4 hv; hv[0]=h0[0]; hv[1]=h0[1]; hv[2]=h1[0]; hv[3]=h1[1];
        *(f16x4*)(cbl + el*72 + sub*4) = hv;
    }
    __syncthreads();

    const int rowbase = rb*64 + wave*16;
    f16x8 az[2];
    az[0] = *(const f16x8*)&zh[(size_t)(rowbase+col)*64 + quad*8];
    az[1] = *(const f16x8*)&zh[(size_t)(rowbase+col)*64 + quad*8 + 32];

    f32x4 zc; zc[0]=0.f; zc[1]=0.f; zc[2]=0.f; zc[3]=0.f;
    float best[4] = {__builtin_inff(),__builtin_inff(),__builtin_inff(),__builtin_inff()};
    int   bidx[4] = {0,0,0,0};

    #pragma unroll 4
    for (int nt=0; nt<16; nt++){
        const int el = nt*16 + col;
        f16x8 c0 = *(const f16x8*)&cbl[el*72 + quad*8];
        f16x8 c1 = *(const f16x8*)&cbl[el*72 + quad*8 + 32];
        float cnc = cnorm[ns*256 + el];
        f32x4 acc = __builtin_amdgcn_mfma_f32_16x16x32_f16(az[0], c0, zc, 0,0,0);
        acc = __builtin_amdgcn_mfma_f32_16x16x32_f16(az[1], c1, acc, 0,0,0);
        const int myidx = ns*256 + el;
        #pragma unroll
        for (int r=0; r<4; r++){
            float d = fmaf(-2.0f, acc[r], cnc);
            if (d < best[r]){ best[r] = d; bidx[r] = myidx; }
        }
    }

    #pragma unroll
    for (int r=0; r<4; r++){
        float v = best[r]; int i = bidx[r];
        #pragma unroll
        for (int s=1; s<16; s<<=1){
            float ov = __shfl_xor(v, s, 64);
            int   oi = __shfl_xor(i, s, 64);
            if (ov < v || (ov == v && oi < i)){ v = ov; i = oi; }
        }
        if (col == 0){
            int row = rowbase + quad*4 + r;
            pval[row*32 + ns] = v;
            pidx[row*32 + ns] = i;
        }
    }
}

// ---------------- decoder (argmin-merge + 64->128->64->3) + per-b loss partial ----------------
__global__ __launch_bounds__(128, 2) void decoder_kernel(
    const float* __restrict__ z,
    const float* __restrict__ pval, const int* __restrict__ pidx,
    const float* __restrict__ cb,
    const float* __restrict__ U1, const float* __restrict__ c1,
    const float* __restrict__ U2, const float* __restrict__ c2,
    const float* __restrict__ U3, const float* __restrict__ c3,
    float* __restrict__ xrec, float* __restrict__ loss_part)
{
    const int b = blockIdx.x;
    const int t = threadIdx.x;
    __shared__ int kk_s;
    __shared__ float zst[64];
    __shared__ float g1[128];
    __shared__ float g2[64];
    if (t < 32){
        float v = pval[b*32 + t]; int i = pidx[b*32 + t];
        #pragma unroll
        for (int s=1; s<32; s<<=1){
            float ov = __shfl_xor(v, s, 32);
            int   oi = __shfl_xor(i, s, 32);
            if (ov < v || (ov == v && oi < i)){ v = ov; i = oi; }
        }
        if (t==0) kk_s = i;
    }
    __syncthreads();
    const int kk = kk_s;
    if (t < 64){
        float zv = z[(size_t)b*64 + t];
        float zq = cb[(size_t)kk*64 + t];
        float diff = zq - zv;
        zst[t] = zv + diff;
        float p = diff*diff;
        #pragma unroll
        for (int s=32;s>0;s>>=1) p += __shfl_xor(p, s, 64);
        if (t==0) loss_part[b] = p;
    }
    __syncthreads();
    {
        float v = c1[t];
        #pragma unroll
        for (int d=0; d<64; d++) v = fmaf(zst[d], U1[d*128+t], v);
        g1[t] = leakyf(v);
    }
    __syncthreads();
    if (t < 64){
        float v = c2[t];
        #pragma unroll
        for (int j=0;j<128;j++) v = fmaf(g1[j], U2[j*64+t], v);
        g2[t] = leakyf(v);
    }
    __syncthreads();
    if (t < 3){
        float v = c3[t];
        #pragma unroll
        for (int j=0;j<64;j++) v = fmaf(g2[j], U3[j*3+t], v);
        xrec[(size_t)b*3 + t] = v;
    }
}

__global__ __launch_bounds__(256, 1) void loss_kernel(
    const float* __restrict__ loss_part, float* __restrict__ out)
{
    const int t = threadIdx.x;
    float s = 0.f;
    for (int i=t;i<BB;i+=256) s += loss_part[i];
    #pragma unroll
    for (int sh=32;sh>0;sh>>=1) s += __shfl_xor(s, sh, 64);
    __shared__ float w[4];
    if ((t&63)==0) w[t>>6] = s;
    __syncthreads();
    if (t==0) out[0] = (w[0]+w[1]+w[2]+w[3]) * (1.25f / 65536.0f);
}

extern "C" void kernel_launch(void* const* d_in, const int* in_sizes, int n_in,
                              void* d_out, int out_size, void* d_ws, size_t ws_size,
                              hipStream_t stream)
{
    const float* x  = (const float*)d_in[0];
    const float* W1 = (const float*)d_in[1];
    const float* b1 = (const float*)d_in[2];
    const float* W2 = (const float*)d_in[3];
    const float* b2 = (const float*)d_in[4];
    const float* W3 = (const float*)d_in[5];
    const float* b3 = (const float*)d_in[6];
    const float* cb = (const float*)d_in[7];
    const float* U1 = (const float*)d_in[8];
    const float* c1 = (const float*)d_in[9];
    const float* U2 = (const float*)d_in[10];
    const float* c2 = (const float*)d_in[11];
    const float* U3 = (const float*)d_in[12];
    const float* c3 = (const float*)d_in[13];

    float* out  = (float*)d_out;
    float* xrec = out;              // [1024*3]
    float* loss = out + 3072;       // [1]
    float* z    = out + 3073;       // [1024*64]

    char* ws = (char*)d_ws;
    float*    lp    = (float*)ws;                       // 4 KB
    _Float16* zh    = (_Float16*)(ws + 4096);           // 128 KB
    float*    pval  = (float*)(ws + 135168);            // 128 KB
    int*      pidx  = (int*)(ws + 266240);              // 128 KB
    float*    cnorm = (float*)(ws + 397312);            // 32 KB

    hipLaunchKernelGGL(cnorm_kernel, dim3(KK/256), dim3(256), 0, stream, cb, cnorm);
    hipLaunchKernelGGL(encoder_mfma, dim3(BB), dim3(256), 0, stream,
                       x, W1, b1, W2, b2, W3, b3, z, zh);
    hipLaunchKernelGGL(vq_mfma, dim3(512), dim3(256), 0, stream, zh, cb, cnorm, pval, pidx);
    hipLaunchKernelGGL(decoder_kernel, dim3(BB), dim3(128), 0, stream,
                       z, pval, pidx, cb, U1, c1, U2, c2, U3, c3, xrec, lp);
    hipLaunchKernelGGL(loss_kernel, dim3(1), dim3(256), 0, stream, lp, loss);
}